// Round 2
// baseline (61.530 us; speedup 1.0000x reference)
//
#include <hip/hip_runtime.h>

#define NUM_INPUT   256
#define NUM_OUTPUT  64
#define MAX_DEPTH   10
#define N_INTERNAL  1023
#define STAGED_NODES 63          // tree levels 0..5 staged in LDS
#define STAGED_DEPTH 6
#define WAVES_PER_BLOCK 16
#define THREADS (WAVES_PER_BLOCK * 64)   // 1024
#define BLOCKS 256                        // persistent: 1 block per CU
#define ELEMS_PER_WAVE_TOTAL 32           // 131072 / (256*16)
#define ROUNDS 4                          // 2 chains x 4 elems per round

__global__ __launch_bounds__(THREADS) void ogtree_kernel(
    const float* __restrict__ x,
    const float* __restrict__ W,
    const float* __restrict__ b,
    const float* __restrict__ alpha,
    const float* __restrict__ leaves,
    float* __restrict__ out)
{
    __shared__ float lds_w[STAGED_NODES * NUM_INPUT];  // 63 KB
    __shared__ float lds_b[N_INTERNAL];                // 4 KB
    __shared__ float lds_a[N_INTERNAL];                // 4 KB

    const int tid = threadIdx.x;

    // ---- stage W levels 0..5 (rows 0..62) + all b/alpha — ONCE per CU ----
    {
        const float4* Wv = reinterpret_cast<const float4*>(W);
        float4* lw4 = reinterpret_cast<float4*>(lds_w);
        #pragma unroll
        for (int i = tid; i < STAGED_NODES * NUM_INPUT / 4; i += THREADS)
            lw4[i] = Wv[i];
        for (int i = tid; i < N_INTERNAL; i += THREADS) {
            lds_b[i] = b[i];
            lds_a[i] = alpha[i];
        }
    }
    __syncthreads();

    const int lane = tid & 63;
    const int wid  = tid >> 6;
    const int g    = lane >> 4;   // element slot within chain (0..3)
    const int s    = lane & 15;   // sub-lane within 16-lane element group
    const int wave_base = (blockIdx.x * WAVES_PER_BLOCK + wid) * ELEMS_PER_WAVE_TOTAL;

    for (int r = 0; r < ROUNDS; ++r) {
        const int elemA = wave_base + r * 8 + g;      // chain A: 4 elems
        const int elemB = elemA + 4;                  // chain B: next 4 elems

        // x fragments: 16 floats/lane per chain, coalesced 256B per group
        const float4* xrA = reinterpret_cast<const float4*>(x + (size_t)elemA * NUM_INPUT);
        const float4* xrB = reinterpret_cast<const float4*>(x + (size_t)elemB * NUM_INPUT);
        float4 xa[4], xb[4];
        #pragma unroll
        for (int k = 0; k < 4; ++k) {
            xa[k] = xrA[k * 16 + s];
            xb[k] = xrB[k * 16 + s];
        }

        int   idxA = 0,   idxB = 0;
        float multA = 1.f, multB = 1.f;

        #pragma unroll
        for (int d = 0; d < MAX_DEPTH; ++d) {
            const float4* wrA;
            const float4* wrB;
            if (d < STAGED_DEPTH) {
                wrA = reinterpret_cast<const float4*>(lds_w + idxA * NUM_INPUT);
                wrB = reinterpret_cast<const float4*>(lds_w + idxB * NUM_INPUT);
            } else {
                wrA = reinterpret_cast<const float4*>(W + (size_t)idxA * NUM_INPUT);
                wrB = reinterpret_cast<const float4*>(W + (size_t)idxB * NUM_INPUT);
            }
            float accA = 0.f, accB = 0.f;
            #pragma unroll
            for (int k = 0; k < 4; ++k) {
                float4 wa = wrA[k * 16 + s];
                float4 wb = wrB[k * 16 + s];
                accA = fmaf(xa[k].x, wa.x, accA);
                accA = fmaf(xa[k].y, wa.y, accA);
                accA = fmaf(xa[k].z, wa.z, accA);
                accA = fmaf(xa[k].w, wa.w, accA);
                accB = fmaf(xb[k].x, wb.x, accB);
                accB = fmaf(xb[k].y, wb.y, accB);
                accB = fmaf(xb[k].z, wb.z, accB);
                accB = fmaf(xb[k].w, wb.w, accB);
            }
            #pragma unroll
            for (int m = 1; m <= 8; m <<= 1) {
                accA += __shfl_xor(accA, m);
                accB += __shfl_xor(accB, m);
            }
            // numerics identical to the passing R1 kernel
            float zA = lds_a[idxA] * (accA + lds_b[idxA]);
            float zB = lds_a[idxB] * (accB + lds_b[idxB]);
            float vA = 1.0f / (1.0f + __expf(-zA));
            float vB = 1.0f / (1.0f + __expf(-zB));
            bool  rA = vA >= 0.5f;
            bool  rB = vB >= 0.5f;
            multA *= rA ? vA : (1.0f - vA);
            multB *= rB ? vB : (1.0f - vB);
            idxA = 2 * idxA + 1 + (rA ? 1 : 0);
            idxB = 2 * idxB + 1 + (rB ? 1 : 0);
        }

        // ---- epilogue ----
        const float4 lvA = reinterpret_cast<const float4*>(
            leaves + (size_t)(idxA - N_INTERNAL) * NUM_OUTPUT)[s];
        const float4 lvB = reinterpret_cast<const float4*>(
            leaves + (size_t)(idxB - N_INTERNAL) * NUM_OUTPUT)[s];
        float4 oA, oB;
        oA.x = multA * lvA.x; oA.y = multA * lvA.y;
        oA.z = multA * lvA.z; oA.w = multA * lvA.w;
        oB.x = multB * lvB.x; oB.y = multB * lvB.y;
        oB.z = multB * lvB.z; oB.w = multB * lvB.w;
        reinterpret_cast<float4*>(out + (size_t)elemA * NUM_OUTPUT)[s] = oA;
        reinterpret_cast<float4*>(out + (size_t)elemB * NUM_OUTPUT)[s] = oB;
    }
}

extern "C" void kernel_launch(void* const* d_in, const int* in_sizes, int n_in,
                              void* d_out, int out_size, void* d_ws, size_t ws_size,
                              hipStream_t stream) {
    const float* x      = (const float*)d_in[0];
    const float* W      = (const float*)d_in[1];
    const float* b      = (const float*)d_in[2];
    const float* alpha  = (const float*)d_in[3];
    const float* leaves = (const float*)d_in[4];
    float* out = (float*)d_out;

    ogtree_kernel<<<BLOCKS, THREADS, 0, stream>>>(x, W, b, alpha, leaves, out);
}

// Round 3
// 49.723 us; speedup vs baseline: 1.2375x; 1.2375x over previous
//
#include <hip/hip_runtime.h>

#define NUM_INPUT   256
#define NUM_OUTPUT  64
#define MAX_DEPTH   10
#define N_INTERNAL  1023
#define STAGED_NODES 63          // tree levels 0..5 staged in LDS
#define STAGED_DEPTH 6
#define ELEMS_PER_WAVE 4         // 16 lanes per element
#define WAVES_PER_BLOCK 16
#define THREADS (WAVES_PER_BLOCK * 64)          // 1024
#define ELEMS_PER_BLOCK (WAVES_PER_BLOCK * ELEMS_PER_WAVE)  // 64

// Sum-reduce across each 16-lane row using DPP row_ror (VALU pipe, no DS ops).
// Rotation by 1,2,4,8 within a 16-lane row leaves every lane with the row sum.
__device__ __forceinline__ float group16_reduce(float acc) {
    int t;
    t = __builtin_amdgcn_update_dpp(0, __float_as_int(acc), 0x121, 0xf, 0xf, true); // row_ror:1
    acc += __int_as_float(t);
    t = __builtin_amdgcn_update_dpp(0, __float_as_int(acc), 0x122, 0xf, 0xf, true); // row_ror:2
    acc += __int_as_float(t);
    t = __builtin_amdgcn_update_dpp(0, __float_as_int(acc), 0x124, 0xf, 0xf, true); // row_ror:4
    acc += __int_as_float(t);
    t = __builtin_amdgcn_update_dpp(0, __float_as_int(acc), 0x128, 0xf, 0xf, true); // row_ror:8
    acc += __int_as_float(t);
    return acc;
}

__global__ __launch_bounds__(THREADS) void ogtree_kernel(
    const float* __restrict__ x,
    const float* __restrict__ W,
    const float* __restrict__ b,
    const float* __restrict__ alpha,
    const float* __restrict__ leaves,
    float* __restrict__ out)
{
    __shared__ float lds_w[STAGED_NODES * NUM_INPUT];  // 63 KB
    __shared__ float lds_b[N_INTERNAL];                // 4 KB
    __shared__ float lds_a[N_INTERNAL];                // 4 KB

    const int tid = threadIdx.x;

    // ---- stage W levels 0..5 (contiguous rows 0..62) + all b/alpha ----
    {
        const float4* Wv = reinterpret_cast<const float4*>(W);
        float4* lw4 = reinterpret_cast<float4*>(lds_w);
        #pragma unroll
        for (int i = tid; i < STAGED_NODES * NUM_INPUT / 4; i += THREADS)
            lw4[i] = Wv[i];
        for (int i = tid; i < N_INTERNAL; i += THREADS) {
            lds_b[i] = b[i];
            lds_a[i] = alpha[i];
        }
    }
    __syncthreads();

    const int lane = tid & 63;
    const int wid  = tid >> 6;
    const int g    = lane >> 4;   // element slot within wave (0..3)
    const int s    = lane & 15;   // sub-lane within element group
    const int elem = blockIdx.x * ELEMS_PER_BLOCK + wid * ELEMS_PER_WAVE + g;

    // ---- x fragment: 16 floats per lane, coalesced 256B per 16-lane group ----
    const float4* xrow = reinterpret_cast<const float4*>(x + (size_t)elem * NUM_INPUT);
    float4 xv[4];
    #pragma unroll
    for (int k = 0; k < 4; ++k)
        xv[k] = xrow[k * 16 + s];   // features k*64 + s*4 .. +3

    int   idx  = 0;
    float mult = 1.0f;

    // ---- depths 0..5: W from LDS ----
    #pragma unroll
    for (int d = 0; d < STAGED_DEPTH; ++d) {
        const float4* wrow = reinterpret_cast<const float4*>(lds_w + idx * NUM_INPUT);
        float acc = 0.0f;
        #pragma unroll
        for (int k = 0; k < 4; ++k) {
            float4 wv = wrow[k * 16 + s];
            acc = fmaf(xv[k].x, wv.x, acc);
            acc = fmaf(xv[k].y, wv.y, acc);
            acc = fmaf(xv[k].z, wv.z, acc);
            acc = fmaf(xv[k].w, wv.w, acc);
        }
        acc = group16_reduce(acc);
        float z   = lds_a[idx] * (acc + lds_b[idx]);
        float val = 1.0f / (1.0f + __expf(-z));
        bool  right = (val >= 0.5f);
        mult *= right ? val : (1.0f - val);
        idx = 2 * idx + 1 + (right ? 1 : 0);
    }

    // ---- depths 6..9: W from global (L2-resident, 1 MB) ----
    #pragma unroll
    for (int d = STAGED_DEPTH; d < MAX_DEPTH; ++d) {
        const float4* wrow = reinterpret_cast<const float4*>(W + (size_t)idx * NUM_INPUT);
        float acc = 0.0f;
        #pragma unroll
        for (int k = 0; k < 4; ++k) {
            float4 wv = wrow[k * 16 + s];
            acc = fmaf(xv[k].x, wv.x, acc);
            acc = fmaf(xv[k].y, wv.y, acc);
            acc = fmaf(xv[k].z, wv.z, acc);
            acc = fmaf(xv[k].w, wv.w, acc);
        }
        acc = group16_reduce(acc);
        float z   = lds_a[idx] * (acc + lds_b[idx]);
        float val = 1.0f / (1.0f + __expf(-z));
        bool  right = (val >= 0.5f);
        mult *= right ? val : (1.0f - val);
        idx = 2 * idx + 1 + (right ? 1 : 0);
    }

    // ---- epilogue: out[elem] = mult * leaves[idx - 1023] ----
    const int leaf = idx - N_INTERNAL;
    const float4 lv = reinterpret_cast<const float4*>(
        leaves + (size_t)leaf * NUM_OUTPUT)[s];
    float4 o;
    o.x = mult * lv.x;
    o.y = mult * lv.y;
    o.z = mult * lv.z;
    o.w = mult * lv.w;
    reinterpret_cast<float4*>(out + (size_t)elem * NUM_OUTPUT)[s] = o;
}

extern "C" void kernel_launch(void* const* d_in, const int* in_sizes, int n_in,
                              void* d_out, int out_size, void* d_ws, size_t ws_size,
                              hipStream_t stream) {
    const float* x      = (const float*)d_in[0];
    const float* W      = (const float*)d_in[1];
    const float* b      = (const float*)d_in[2];
    const float* alpha  = (const float*)d_in[3];
    const float* leaves = (const float*)d_in[4];
    float* out = (float*)d_out;

    const int batch  = in_sizes[0] / NUM_INPUT;           // 131072
    const int blocks = batch / ELEMS_PER_BLOCK;           // 2048

    ogtree_kernel<<<blocks, THREADS, 0, stream>>>(x, W, b, alpha, leaves, out);
}